// Round 13
// baseline (186.909 us; speedup 1.0000x reference)
//
#include <hip/hip_runtime.h>
#include <hip/hip_bf16.h>

// GDGCN: out[b,c,m,t] = sum_n softmax_row(relu(t1 nv2^T))[n,m] * x[b,c,n,t]
// t1 = nv1 @ (sum_d tv[d] k[d,:,:]);  N=8192, D=32, cols = B*C*T = 192.
// R24: 4-kernel pipeline (R23: non-mega 101->93us, keep) + k_mega restored
// to R21's EXACT proven interleave (71us). Normalization stays E-side as
// log2-bias via gen-MFMA C-in, but with the early-fmax trick:
//   m = fmax(d, bv) computed right after gen -> d and bv die before the
//   12-MFMA acc block; only m0,m1 (8 VGPR) live across, same profile as
//   R21's d0,d1. Pack (exp2+f2bf) stays after acc k0 (R21 order; R23's
//   pack-before-acc serialized the stage and cost 18us, MfmaUtil 15.7->13.1).
// Proven invariants: col-split waves + LDS-E dbuf (m-splits all lost),
// stage-top loads (R19), RAWBAR lgkmcnt-only, ESTR 70, setprio, bf16
// part, RNE f2bf pack only (v_cvt_pk_bf16_f32 NOT RNE on gfx950, R14).

#define NN 8192
#define DD 32
#define TT 12
#define NSPLIT 8
#define CHUNK 1024
#define ESTR 70  // LDS row stride (ushort)

typedef __attribute__((ext_vector_type(8))) short bf16x8;
typedef __attribute__((ext_vector_type(4))) short bf16x4;
typedef __attribute__((ext_vector_type(4))) float f32x4;

static __device__ __forceinline__ unsigned short f2bf(float f) {
  unsigned int u = __float_as_uint(f);
  u = (u + 0x7FFFu + ((u >> 16) & 1u)) >> 16;  // RNE bf16
  return (unsigned short)u;
}

static __device__ __forceinline__ float fexp2(float x) {
#if __has_builtin(__builtin_amdgcn_exp2f)
  return __builtin_amdgcn_exp2f(x);
#else
  return __builtin_exp2f(x);
#endif
}

static __device__ __forceinline__ float flog2(float x) {
#if __has_builtin(__builtin_amdgcn_logf)
  return __builtin_amdgcn_logf(x);
#else
  return __log2f(x);
#endif
}

// Raw barrier: LDS-visibility only (lgkmcnt). Global loads stay in flight.
#define RAWBAR()                                          \
  do {                                                    \
    asm volatile("s_waitcnt lgkmcnt(0)" ::: "memory");    \
    __builtin_amdgcn_sched_barrier(0);                    \
    __builtin_amdgcn_s_barrier();                         \
  } while (0)

// ---- k_pre: core = tv.k ; t1 rows ; nv2 -> bf16 ; yT = bf16(x) transpose ----
// 512 blocks: block b = (bc = b>>5, xb = b&31).
__global__ __launch_bounds__(256) void k_pre(const float* __restrict__ x,
                                             const float* __restrict__ nv1,
                                             const float* __restrict__ nv2,
                                             const float* __restrict__ timevec,
                                             const float* __restrict__ kk,
                                             const int* __restrict__ tind,
                                             unsigned short* __restrict__ t1b,
                                             unsigned short* __restrict__ nv2b,
                                             unsigned short* __restrict__ yT) {
  __shared__ float cs[1024];
  __shared__ float xs[3328];  // 256 * 13 (pad kills stride-12 conflicts)
  const int tid = threadIdx.x;
  const int bid = blockIdx.x;
  const int bc = bid >> 5, xb = bid & 31;
  const int n0 = xb * 256;

  const float* tv = timevec + (size_t)tind[0] * DD;
  for (int idx = tid; idx < 1024; idx += 256) {
    float acc = 0.f;
#pragma unroll
    for (int d = 0; d < DD; ++d) acc += tv[d] * kk[d * 1024 + idx];
    cs[idx] = acc;
  }
  const float* xp = x + (size_t)bc * NN * TT + (size_t)n0 * TT;
#pragma unroll
  for (int j = 0; j < 12; ++j) {
    const int idx = j * 256 + tid;
    xs[(idx / 12) * 13 + idx % 12] = xp[idx];
  }
  __syncthreads();

  const int f = tid & 31, sub = tid >> 5;
  const int tb = bid * 16;
#pragma unroll
  for (int it = 0; it < 2; ++it) {
    const int n = tb + it * 8 + sub;
    const float* nr = nv1 + (size_t)n * DD;
    float acc = 0.f;
#pragma unroll
    for (int e = 0; e < DD; ++e) acc += nr[e] * cs[e * DD + f];
    t1b[(size_t)n * DD + f] = f2bf(acc * 1.4426950408889634f);  // fold log2(e)
  }
#pragma unroll
  for (int it = 0; it < 2; ++it) {
    const int idx = bid * 512 + it * 256 + tid;
    nv2b[idx] = f2bf(nv2[idx]);
  }
#pragma unroll
  for (int t = 0; t < 12; ++t)
    yT[(size_t)(bc * TT + t) * NN + n0 + tid] = f2bf(xs[tid * 13 + t]);
}

// ---- sums_part[j][n] = sum_{m in chunk j} exp2(relu(t1[n].nv2[m])) ----
// grid (128 n, 8 m-chunks of 1024); no atomics, no init, deterministic.
__global__ __launch_bounds__(256) void k_stats(const unsigned short* __restrict__ t1b,
                                               const unsigned short* __restrict__ nv2b,
                                               float* __restrict__ sumsp) {
  const int tid = threadIdx.x;
  const int w = tid >> 6, lane = tid & 63, q = lane >> 4, i16 = lane & 15;
  const int nbase = blockIdx.x * 64 + w * 16;
  bf16x8 a = *(const bf16x8*)(t1b + (size_t)(nbase + i16) * DD + q * 8);
  const f32x4 z4 = {0.f, 0.f, 0.f, 0.f};
  float s[4] = {0.f, 0.f, 0.f, 0.f};
  const int m0 = blockIdx.y * 1024;
#define LDB(mt, u) (*(const bf16x8*)(nv2b + (size_t)((mt) + (u)*16 + i16) * DD + q * 8))
  bf16x8 b0 = LDB(m0, 0), b1 = LDB(m0, 1), b2 = LDB(m0, 2), b3 = LDB(m0, 3);
  for (int mt = m0; mt < m0 + 1024; mt += 64) {
    const int mtn = (mt + 64 < m0 + 1024) ? (mt + 64) : mt;  // clamp: dummy reload
    bf16x8 n0 = LDB(mtn, 0), n1 = LDB(mtn, 1), n2 = LDB(mtn, 2), n3 = LDB(mtn, 3);
    f32x4 d;
    d = __builtin_amdgcn_mfma_f32_16x16x32_bf16(a, b0, z4, 0, 0, 0);
#pragma unroll
    for (int r = 0; r < 4; ++r) s[r] += fexp2(fmaxf(d[r], 0.f));
    d = __builtin_amdgcn_mfma_f32_16x16x32_bf16(a, b1, z4, 0, 0, 0);
#pragma unroll
    for (int r = 0; r < 4; ++r) s[r] += fexp2(fmaxf(d[r], 0.f));
    d = __builtin_amdgcn_mfma_f32_16x16x32_bf16(a, b2, z4, 0, 0, 0);
#pragma unroll
    for (int r = 0; r < 4; ++r) s[r] += fexp2(fmaxf(d[r], 0.f));
    d = __builtin_amdgcn_mfma_f32_16x16x32_bf16(a, b3, z4, 0, 0, 0);
#pragma unroll
    for (int r = 0; r < 4; ++r) s[r] += fexp2(fmaxf(d[r], 0.f));
    b0 = n0; b1 = n1; b2 = n2; b3 = n3;
  }
#undef LDB
#pragma unroll
  for (int r = 0; r < 4; ++r)
    for (int off = 1; off < 16; off <<= 1) s[r] += __shfl_xor(s[r], off, 64);
  if (i16 == 0) {
#pragma unroll
    for (int r = 0; r < 4; ++r)
      sumsp[(size_t)blockIdx.y * NN + nbase + q * 4 + r] = s[r];
  }
}

// ---- k_mega: part[nc][col][m] = sum_{n in chunk} E'[n][m] * y[col][n] ----
// E' = exp2(max(logit + l2r[n], l2r[n])), l2r = -log2(sum). R21 interleave:
// gen d0,d1 + EARLY fmax -> acc k0 -> pack e0,e1 + gen/pack s2,s3 -> acc k1.
__global__ __launch_bounds__(256, 4) void k_mega(const unsigned short* __restrict__ t1b,
                                                 const unsigned short* __restrict__ nv2b,
                                                 const unsigned short* __restrict__ yT,
                                                 const float* __restrict__ sumsp,
                                                 unsigned short* __restrict__ part) {
  const int tid = threadIdx.x;
  const int w = tid >> 6, lane = tid & 63, q = lane >> 4, i16 = lane & 15;
  const int mb = blockIdx.x * 64;
  const int nt0 = blockIdx.y * CHUNK;

  __shared__ unsigned short Ew[2][64][ESTR];  // 17920 B
  __shared__ f32x4 bias_v[256];               //  4096 B: l2r[1024 n]

  // prologue A: l2r table (deterministic j-order sum, then -log2)
  {
    float* bl = (float*)bias_v;
    for (int k = tid; k < 1024; k += 256) {
      float ssum = 0.f;
#pragma unroll
      for (int j = 0; j < NSPLIT; ++j) ssum += sumsp[(size_t)j * NN + nt0 + k];
      bl[k] = -flog2(ssum);
    }
  }

  // gen B-frag (loop-invariant): B[d][m=i16] = nv2[mb + w*16 + i16][d]
  const bf16x8 bg = *(const bf16x8*)(nv2b + (size_t)(mb + w * 16 + i16) * DD + q * 8);
  const int rowm = w * 16 + i16;

  f32x4 acc[3][4];
#pragma unroll
  for (int c = 0; c < 3; ++c)
#pragma unroll
    for (int ms = 0; ms < 4; ++ms) acc[c][ms] = (f32x4){0.f, 0.f, 0.f, 0.f};

  RAWBAR();  // bias table visible

  // prologue B: generate stage 0 (64 n) into buf 0 (C-in bias + fmax relu)
#pragma unroll
  for (int s = 0; s < 4; ++s) {
    bf16x8 at = *(const bf16x8*)(t1b + (size_t)(nt0 + s * 16 + i16) * DD + q * 8);
    const f32x4 bv = bias_v[s * 4 + q];  // l2r[n = s*16 + q*4 + r]
    f32x4 d = __builtin_amdgcn_mfma_f32_16x16x32_bf16(at, bg, bv, 0, 0, 0);
    bf16x4 e;
#pragma unroll
    for (int r = 0; r < 4; ++r) e[r] = (short)f2bf(fexp2(fmaxf(d[r], bv[r])));
    *(bf16x4*)&Ew[0][rowm][s * 16 + q * 4] = e;
  }
  RAWBAR();

  int p = 0;
  for (int st = 0; st < 16; ++st, p ^= 1) {
    const int nt = nt0 + st * 64;
    const bool more = (st < 15);

    // --- stage top: issue ALL global loads (y both halves, next t1) ---
    bf16x8 yfr0[3], yfr1[3];
#pragma unroll
    for (int c = 0; c < 3; ++c) {
      const unsigned short* ybase = yT + (size_t)((w * 3 + c) * 16 + i16) * NN + nt + q * 8;
      yfr0[c] = *(const bf16x8*)ybase;
      yfr1[c] = *(const bf16x8*)(ybase + 32);
    }
    bf16x8 atn[4];
    if (more) {
#pragma unroll
      for (int s = 0; s < 4; ++s)
        atn[s] = *(const bf16x8*)(t1b + (size_t)(nt + 64 + s * 16 + i16) * DD + q * 8);
    }

    // half-0 E operands
    bf16x8 efr[4];
#pragma unroll
    for (int ms = 0; ms < 4; ++ms)
      efr[ms] = *(const bf16x8*)&Ew[p][ms * 16 + i16][q * 8];

    // gen s0,s1 for stage st+1 + EARLY fmax (bv,d die before acc k0;
    // only m0,m1 = 8 VGPR live across -- same profile as R21's d0,d1)
    f32x4 m0, m1;
    if (more) {
      const f32x4 bv0 = bias_v[(st + 1) * 16 + q];
      const f32x4 bv1 = bias_v[(st + 1) * 16 + 4 + q];
      f32x4 d0 = __builtin_amdgcn_mfma_f32_16x16x32_bf16(atn[0], bg, bv0, 0, 0, 0);
      f32x4 d1 = __builtin_amdgcn_mfma_f32_16x16x32_bf16(atn[1], bg, bv1, 0, 0, 0);
#pragma unroll
      for (int r = 0; r < 4; ++r) {
        m0[r] = fmaxf(d0[r], bv0[r]);
        m1[r] = fmaxf(d1[r], bv1[r]);
      }
    }

    // acc k-step 0 (12 MFMAs), priority-boosted (T5)
    __builtin_amdgcn_s_setprio(1);
#pragma unroll
    for (int c = 0; c < 3; ++c)
#pragma unroll
      for (int ms = 0; ms < 4; ++ms)
        acc[c][ms] = __builtin_amdgcn_mfma_f32_16x16x32_bf16(yfr0[c], efr[ms], acc[c][ms], 0, 0, 0);
    __builtin_amdgcn_s_setprio(0);

    // pack s0,s1 + store; gen s2,s3 + fmax + pack + store (R21 order)
    if (more) {
      bf16x4 e0, e1;
#pragma unroll
      for (int r = 0; r < 4; ++r) {
        e0[r] = (short)f2bf(fexp2(m0[r]));
        e1[r] = (short)f2bf(fexp2(m1[r]));
      }
      *(bf16x4*)&Ew[p ^ 1][rowm][q * 4] = e0;
      *(bf16x4*)&Ew[p ^ 1][rowm][16 + q * 4] = e1;
      const f32x4 bv2 = bias_v[(st + 1) * 16 + 8 + q];
      const f32x4 bv3 = bias_v[(st + 1) * 16 + 12 + q];
      f32x4 d2 = __builtin_amdgcn_mfma_f32_16x16x32_bf16(atn[2], bg, bv2, 0, 0, 0);
      f32x4 d3 = __builtin_amdgcn_mfma_f32_16x16x32_bf16(atn[3], bg, bv3, 0, 0, 0);
      bf16x4 e2, e3;
#pragma unroll
      for (int r = 0; r < 4; ++r) {
        e2[r] = (short)f2bf(fexp2(fmaxf(d2[r], bv2[r])));
        e3[r] = (short)f2bf(fexp2(fmaxf(d3[r], bv3[r])));
      }
      *(bf16x4*)&Ew[p ^ 1][rowm][32 + q * 4] = e2;
      *(bf16x4*)&Ew[p ^ 1][rowm][48 + q * 4] = e3;
    }

    // half-1 E operands + acc (k-step 1: n 32..63)
#pragma unroll
    for (int ms = 0; ms < 4; ++ms)
      efr[ms] = *(const bf16x8*)&Ew[p][ms * 16 + i16][32 + q * 8];
    __builtin_amdgcn_s_setprio(1);
#pragma unroll
    for (int c = 0; c < 3; ++c)
#pragma unroll
      for (int ms = 0; ms < 4; ++ms)
        acc[c][ms] = __builtin_amdgcn_mfma_f32_16x16x32_bf16(yfr1[c], efr[ms], acc[c][ms], 0, 0, 0);
    __builtin_amdgcn_s_setprio(0);

    RAWBAR();  // buf p reads done; buf p^1 writes visible (lgkmcnt only)
  }

  // epilogue: lane holds col = (w*3+c)*16 + q*4 + r, m = mb + ms*16 + i16
  unsigned short* pp = part + (size_t)blockIdx.y * 192 * NN;
#pragma unroll
  for (int c = 0; c < 3; ++c)
#pragma unroll
    for (int ms = 0; ms < 4; ++ms) {
      const int colbase = (w * 3 + c) * 16 + q * 4;
      const int m = mb + ms * 16 + i16;
#pragma unroll
      for (int r = 0; r < 4; ++r)
        pp[(size_t)(colbase + r) * NN + m] = f2bf(acc[c][ms][r]);
    }
}

// ---- reduce NSPLIT bf16 partials + transpose to out[bc][m][t] (pad 12->13) ----
__global__ __launch_bounds__(256) void k_reduce(const unsigned short* __restrict__ part,
                                                float* __restrict__ out) {
  __shared__ float os[3328];  // 256 * 13
  const int tid = threadIdx.x;
  const int m0 = blockIdx.x * 256;
  const int bc = blockIdx.y;
#pragma unroll
  for (int t = 0; t < 12; ++t) {
    const int col = bc * TT + t;
    float s = 0.f;
#pragma unroll
    for (int nc = 0; nc < NSPLIT; ++nc) {
      const unsigned int u = part[((size_t)nc * 192 + col) * NN + m0 + tid];
      s += __uint_as_float(u << 16);
    }
    os[tid * 13 + t] = s;
  }
  __syncthreads();
  float* op = out + (size_t)bc * NN * TT + (size_t)m0 * TT;
#pragma unroll
  for (int j = 0; j < 12; ++j) {
    const int idx = j * 256 + tid;
    op[idx] = os[(idx / 12) * 13 + idx % 12];
  }
}

extern "C" void kernel_launch(void* const* d_in, const int* in_sizes, int n_in,
                              void* d_out, int out_size, void* d_ws, size_t ws_size,
                              hipStream_t stream) {
  const float* x = (const float*)d_in[0];
  const float* nv1 = (const float*)d_in[1];
  const float* nv2 = (const float*)d_in[2];
  const float* tv = (const float*)d_in[3];
  const float* kk = (const float*)d_in[4];
  const int* tind = (const int*)d_in[5];
  float* out = (float*)d_out;

  char* ws = (char*)d_ws;
  unsigned short* t1b  = (unsigned short*)(ws);            //  524288 B
  unsigned short* nv2b = (unsigned short*)(ws + 524288);   //  524288 B
  float* sumsp         = (float*)(ws + 1048576);           //  262144 B (8 x 8192 f32)
  unsigned short* yT   = (unsigned short*)(ws + 1310720);  // 3145728 B -> 4456448
  unsigned short* part = (unsigned short*)(ws + 4456448);  // 25165824 B (bf16)

  k_pre<<<512, 256, 0, stream>>>(x, nv1, nv2, tv, kk, tind, t1b, nv2b, yT);
  k_stats<<<dim3(128, NSPLIT), 256, 0, stream>>>(t1b, nv2b, sumsp);
  k_mega<<<dim3(128, NSPLIT), 256, 0, stream>>>(t1b, nv2b, yT, sumsp, part);
  k_reduce<<<dim3(32, 16), 256, 0, stream>>>(part, out);
}

// Round 14
// 183.938 us; speedup vs baseline: 1.0162x; 1.0162x over previous
//
#include <hip/hip_runtime.h>
#include <hip/hip_bf16.h>

// GDGCN: out[b,c,m,t] = sum_n softmax_row(relu(t1 nv2^T))[n,m] * x[b,c,n,t]
// t1 = nv1 @ (sum_d tv[d] k[d,:,:]);  N=8192, D=32, cols = B*C*T = 192.
// R25 == R24 with ONE change: k_mega __launch_bounds__(256,4) -> (256,3).
// R22/R23/R24 all spilled (WRITE_SIZE 85/29/48 MB vs 24.6 ideal): the
// (256,4) cap = 128 regs/wave was exactly R21's edge; the bias table's
// extra liveness tips it over no matter the schedule. R21's MEASURED
// occupancy was only ~10.5 waves/CU (33%) -- the 16-wave cap was never
// achieved -- so (256,3) raises the allocator budget to 170 regs/wave
// (no spill) while giving up nothing real.
// Structure: 4-kernel pipeline (non-mega 93us), k_mega = R21's proven
// interleave with normalization as log2-bias via gen-MFMA C-in + early
// fmax. Proven invariants: col-split waves + LDS-E dbuf, stage-top loads,
// RAWBAR lgkmcnt-only, ESTR 70, setprio, bf16 part, RNE f2bf pack only
// (v_cvt_pk_bf16_f32 NOT RNE on gfx950, R14).

#define NN 8192
#define DD 32
#define TT 12
#define NSPLIT 8
#define CHUNK 1024
#define ESTR 70  // LDS row stride (ushort)

typedef __attribute__((ext_vector_type(8))) short bf16x8;
typedef __attribute__((ext_vector_type(4))) short bf16x4;
typedef __attribute__((ext_vector_type(4))) float f32x4;

static __device__ __forceinline__ unsigned short f2bf(float f) {
  unsigned int u = __float_as_uint(f);
  u = (u + 0x7FFFu + ((u >> 16) & 1u)) >> 16;  // RNE bf16
  return (unsigned short)u;
}

static __device__ __forceinline__ float fexp2(float x) {
#if __has_builtin(__builtin_amdgcn_exp2f)
  return __builtin_amdgcn_exp2f(x);
#else
  return __builtin_exp2f(x);
#endif
}

static __device__ __forceinline__ float flog2(float x) {
#if __has_builtin(__builtin_amdgcn_logf)
  return __builtin_amdgcn_logf(x);
#else
  return __log2f(x);
#endif
}

// Raw barrier: LDS-visibility only (lgkmcnt). Global loads stay in flight.
#define RAWBAR()                                          \
  do {                                                    \
    asm volatile("s_waitcnt lgkmcnt(0)" ::: "memory");    \
    __builtin_amdgcn_sched_barrier(0);                    \
    __builtin_amdgcn_s_barrier();                         \
  } while (0)

// ---- k_pre: core = tv.k ; t1 rows ; nv2 -> bf16 ; yT = bf16(x) transpose ----
// 512 blocks: block b = (bc = b>>5, xb = b&31).
__global__ __launch_bounds__(256) void k_pre(const float* __restrict__ x,
                                             const float* __restrict__ nv1,
                                             const float* __restrict__ nv2,
                                             const float* __restrict__ timevec,
                                             const float* __restrict__ kk,
                                             const int* __restrict__ tind,
                                             unsigned short* __restrict__ t1b,
                                             unsigned short* __restrict__ nv2b,
                                             unsigned short* __restrict__ yT) {
  __shared__ float cs[1024];
  __shared__ float xs[3328];  // 256 * 13 (pad kills stride-12 conflicts)
  const int tid = threadIdx.x;
  const int bid = blockIdx.x;
  const int bc = bid >> 5, xb = bid & 31;
  const int n0 = xb * 256;

  const float* tv = timevec + (size_t)tind[0] * DD;
  for (int idx = tid; idx < 1024; idx += 256) {
    float acc = 0.f;
#pragma unroll
    for (int d = 0; d < DD; ++d) acc += tv[d] * kk[d * 1024 + idx];
    cs[idx] = acc;
  }
  const float* xp = x + (size_t)bc * NN * TT + (size_t)n0 * TT;
#pragma unroll
  for (int j = 0; j < 12; ++j) {
    const int idx = j * 256 + tid;
    xs[(idx / 12) * 13 + idx % 12] = xp[idx];
  }
  __syncthreads();

  const int f = tid & 31, sub = tid >> 5;
  const int tb = bid * 16;
#pragma unroll
  for (int it = 0; it < 2; ++it) {
    const int n = tb + it * 8 + sub;
    const float* nr = nv1 + (size_t)n * DD;
    float acc = 0.f;
#pragma unroll
    for (int e = 0; e < DD; ++e) acc += nr[e] * cs[e * DD + f];
    t1b[(size_t)n * DD + f] = f2bf(acc * 1.4426950408889634f);  // fold log2(e)
  }
#pragma unroll
  for (int it = 0; it < 2; ++it) {
    const int idx = bid * 512 + it * 256 + tid;
    nv2b[idx] = f2bf(nv2[idx]);
  }
#pragma unroll
  for (int t = 0; t < 12; ++t)
    yT[(size_t)(bc * TT + t) * NN + n0 + tid] = f2bf(xs[tid * 13 + t]);
}

// ---- sums_part[j][n] = sum_{m in chunk j} exp2(relu(t1[n].nv2[m])) ----
// grid (128 n, 8 m-chunks of 1024); no atomics, no init, deterministic.
__global__ __launch_bounds__(256) void k_stats(const unsigned short* __restrict__ t1b,
                                               const unsigned short* __restrict__ nv2b,
                                               float* __restrict__ sumsp) {
  const int tid = threadIdx.x;
  const int w = tid >> 6, lane = tid & 63, q = lane >> 4, i16 = lane & 15;
  const int nbase = blockIdx.x * 64 + w * 16;
  bf16x8 a = *(const bf16x8*)(t1b + (size_t)(nbase + i16) * DD + q * 8);
  const f32x4 z4 = {0.f, 0.f, 0.f, 0.f};
  float s[4] = {0.f, 0.f, 0.f, 0.f};
  const int m0 = blockIdx.y * 1024;
#define LDB(mt, u) (*(const bf16x8*)(nv2b + (size_t)((mt) + (u)*16 + i16) * DD + q * 8))
  bf16x8 b0 = LDB(m0, 0), b1 = LDB(m0, 1), b2 = LDB(m0, 2), b3 = LDB(m0, 3);
  for (int mt = m0; mt < m0 + 1024; mt += 64) {
    const int mtn = (mt + 64 < m0 + 1024) ? (mt + 64) : mt;  // clamp: dummy reload
    bf16x8 n0 = LDB(mtn, 0), n1 = LDB(mtn, 1), n2 = LDB(mtn, 2), n3 = LDB(mtn, 3);
    f32x4 d;
    d = __builtin_amdgcn_mfma_f32_16x16x32_bf16(a, b0, z4, 0, 0, 0);
#pragma unroll
    for (int r = 0; r < 4; ++r) s[r] += fexp2(fmaxf(d[r], 0.f));
    d = __builtin_amdgcn_mfma_f32_16x16x32_bf16(a, b1, z4, 0, 0, 0);
#pragma unroll
    for (int r = 0; r < 4; ++r) s[r] += fexp2(fmaxf(d[r], 0.f));
    d = __builtin_amdgcn_mfma_f32_16x16x32_bf16(a, b2, z4, 0, 0, 0);
#pragma unroll
    for (int r = 0; r < 4; ++r) s[r] += fexp2(fmaxf(d[r], 0.f));
    d = __builtin_amdgcn_mfma_f32_16x16x32_bf16(a, b3, z4, 0, 0, 0);
#pragma unroll
    for (int r = 0; r < 4; ++r) s[r] += fexp2(fmaxf(d[r], 0.f));
    b0 = n0; b1 = n1; b2 = n2; b3 = n3;
  }
#undef LDB
#pragma unroll
  for (int r = 0; r < 4; ++r)
    for (int off = 1; off < 16; off <<= 1) s[r] += __shfl_xor(s[r], off, 64);
  if (i16 == 0) {
#pragma unroll
    for (int r = 0; r < 4; ++r)
      sumsp[(size_t)blockIdx.y * NN + nbase + q * 4 + r] = s[r];
  }
}

// ---- k_mega: part[nc][col][m] = sum_{n in chunk} E'[n][m] * y[col][n] ----
// E' = exp2(max(logit + l2r[n], l2r[n])), l2r = -log2(sum). R21 interleave:
// gen d0,d1 + EARLY fmax -> acc k0 -> pack e0,e1 + gen/pack s2,s3 -> acc k1.
__global__ __launch_bounds__(256, 3) void k_mega(const unsigned short* __restrict__ t1b,
                                                 const unsigned short* __restrict__ nv2b,
                                                 const unsigned short* __restrict__ yT,
                                                 const float* __restrict__ sumsp,
                                                 unsigned short* __restrict__ part) {
  const int tid = threadIdx.x;
  const int w = tid >> 6, lane = tid & 63, q = lane >> 4, i16 = lane & 15;
  const int mb = blockIdx.x * 64;
  const int nt0 = blockIdx.y * CHUNK;

  __shared__ unsigned short Ew[2][64][ESTR];  // 17920 B
  __shared__ f32x4 bias_v[256];               //  4096 B: l2r[1024 n]

  // prologue A: l2r table (deterministic j-order sum, then -log2)
  {
    float* bl = (float*)bias_v;
    for (int k = tid; k < 1024; k += 256) {
      float ssum = 0.f;
#pragma unroll
      for (int j = 0; j < NSPLIT; ++j) ssum += sumsp[(size_t)j * NN + nt0 + k];
      bl[k] = -flog2(ssum);
    }
  }

  // gen B-frag (loop-invariant): B[d][m=i16] = nv2[mb + w*16 + i16][d]
  const bf16x8 bg = *(const bf16x8*)(nv2b + (size_t)(mb + w * 16 + i16) * DD + q * 8);
  const int rowm = w * 16 + i16;

  f32x4 acc[3][4];
#pragma unroll
  for (int c = 0; c < 3; ++c)
#pragma unroll
    for (int ms = 0; ms < 4; ++ms) acc[c][ms] = (f32x4){0.f, 0.f, 0.f, 0.f};

  RAWBAR();  // bias table visible

  // prologue B: generate stage 0 (64 n) into buf 0 (C-in bias + fmax relu)
#pragma unroll
  for (int s = 0; s < 4; ++s) {
    bf16x8 at = *(const bf16x8*)(t1b + (size_t)(nt0 + s * 16 + i16) * DD + q * 8);
    const f32x4 bv = bias_v[s * 4 + q];  // l2r[n = s*16 + q*4 + r]
    f32x4 d = __builtin_amdgcn_mfma_f32_16x16x32_bf16(at, bg, bv, 0, 0, 0);
    bf16x4 e;
#pragma unroll
    for (int r = 0; r < 4; ++r) e[r] = (short)f2bf(fexp2(fmaxf(d[r], bv[r])));
    *(bf16x4*)&Ew[0][rowm][s * 16 + q * 4] = e;
  }
  RAWBAR();

  int p = 0;
  for (int st = 0; st < 16; ++st, p ^= 1) {
    const int nt = nt0 + st * 64;
    const bool more = (st < 15);

    // --- stage top: issue ALL global loads (y both halves, next t1) ---
    bf16x8 yfr0[3], yfr1[3];
#pragma unroll
    for (int c = 0; c < 3; ++c) {
      const unsigned short* ybase = yT + (size_t)((w * 3 + c) * 16 + i16) * NN + nt + q * 8;
      yfr0[c] = *(const bf16x8*)ybase;
      yfr1[c] = *(const bf16x8*)(ybase + 32);
    }
    bf16x8 atn[4];
    if (more) {
#pragma unroll
      for (int s = 0; s < 4; ++s)
        atn[s] = *(const bf16x8*)(t1b + (size_t)(nt + 64 + s * 16 + i16) * DD + q * 8);
    }

    // half-0 E operands
    bf16x8 efr[4];
#pragma unroll
    for (int ms = 0; ms < 4; ++ms)
      efr[ms] = *(const bf16x8*)&Ew[p][ms * 16 + i16][q * 8];

    // gen s0,s1 for stage st+1 + EARLY fmax (bv,d die before acc k0)
    f32x4 m0, m1;
    if (more) {
      const f32x4 bv0 = bias_v[(st + 1) * 16 + q];
      const f32x4 bv1 = bias_v[(st + 1) * 16 + 4 + q];
      f32x4 d0 = __builtin_amdgcn_mfma_f32_16x16x32_bf16(atn[0], bg, bv0, 0, 0, 0);
      f32x4 d1 = __builtin_amdgcn_mfma_f32_16x16x32_bf16(atn[1], bg, bv1, 0, 0, 0);
#pragma unroll
      for (int r = 0; r < 4; ++r) {
        m0[r] = fmaxf(d0[r], bv0[r]);
        m1[r] = fmaxf(d1[r], bv1[r]);
      }
    }

    // acc k-step 0 (12 MFMAs), priority-boosted (T5)
    __builtin_amdgcn_s_setprio(1);
#pragma unroll
    for (int c = 0; c < 3; ++c)
#pragma unroll
      for (int ms = 0; ms < 4; ++ms)
        acc[c][ms] = __builtin_amdgcn_mfma_f32_16x16x32_bf16(yfr0[c], efr[ms], acc[c][ms], 0, 0, 0);
    __builtin_amdgcn_s_setprio(0);

    // pack s0,s1 + store; gen s2,s3 + fmax + pack + store (R21 order)
    if (more) {
      bf16x4 e0, e1;
#pragma unroll
      for (int r = 0; r < 4; ++r) {
        e0[r] = (short)f2bf(fexp2(m0[r]));
        e1[r] = (short)f2bf(fexp2(m1[r]));
      }
      *(bf16x4*)&Ew[p ^ 1][rowm][q * 4] = e0;
      *(bf16x4*)&Ew[p ^ 1][rowm][16 + q * 4] = e1;
      const f32x4 bv2 = bias_v[(st + 1) * 16 + 8 + q];
      const f32x4 bv3 = bias_v[(st + 1) * 16 + 12 + q];
      f32x4 d2 = __builtin_amdgcn_mfma_f32_16x16x32_bf16(atn[2], bg, bv2, 0, 0, 0);
      f32x4 d3 = __builtin_amdgcn_mfma_f32_16x16x32_bf16(atn[3], bg, bv3, 0, 0, 0);
      bf16x4 e2, e3;
#pragma unroll
      for (int r = 0; r < 4; ++r) {
        e2[r] = (short)f2bf(fexp2(fmaxf(d2[r], bv2[r])));
        e3[r] = (short)f2bf(fexp2(fmaxf(d3[r], bv3[r])));
      }
      *(bf16x4*)&Ew[p ^ 1][rowm][32 + q * 4] = e2;
      *(bf16x4*)&Ew[p ^ 1][rowm][48 + q * 4] = e3;
    }

    // half-1 E operands + acc (k-step 1: n 32..63)
#pragma unroll
    for (int ms = 0; ms < 4; ++ms)
      efr[ms] = *(const bf16x8*)&Ew[p][ms * 16 + i16][32 + q * 8];
    __builtin_amdgcn_s_setprio(1);
#pragma unroll
    for (int c = 0; c < 3; ++c)
#pragma unroll
      for (int ms = 0; ms < 4; ++ms)
        acc[c][ms] = __builtin_amdgcn_mfma_f32_16x16x32_bf16(yfr1[c], efr[ms], acc[c][ms], 0, 0, 0);
    __builtin_amdgcn_s_setprio(0);

    RAWBAR();  // buf p reads done; buf p^1 writes visible (lgkmcnt only)
  }

  // epilogue: lane holds col = (w*3+c)*16 + q*4 + r, m = mb + ms*16 + i16
  unsigned short* pp = part + (size_t)blockIdx.y * 192 * NN;
#pragma unroll
  for (int c = 0; c < 3; ++c)
#pragma unroll
    for (int ms = 0; ms < 4; ++ms) {
      const int colbase = (w * 3 + c) * 16 + q * 4;
      const int m = mb + ms * 16 + i16;
#pragma unroll
      for (int r = 0; r < 4; ++r)
        pp[(size_t)(colbase + r) * NN + m] = f2bf(acc[c][ms][r]);
    }
}

// ---- reduce NSPLIT bf16 partials + transpose to out[bc][m][t] (pad 12->13) ----
__global__ __launch_bounds__(256) void k_reduce(const unsigned short* __restrict__ part,
                                                float* __restrict__ out) {
  __shared__ float os[3328];  // 256 * 13
  const int tid = threadIdx.x;
  const int m0 = blockIdx.x * 256;
  const int bc = blockIdx.y;
#pragma unroll
  for (int t = 0; t < 12; ++t) {
    const int col = bc * TT + t;
    float s = 0.f;
#pragma unroll
    for (int nc = 0; nc < NSPLIT; ++nc) {
      const unsigned int u = part[((size_t)nc * 192 + col) * NN + m0 + tid];
      s += __uint_as_float(u << 16);
    }
    os[tid * 13 + t] = s;
  }
  __syncthreads();
  float* op = out + (size_t)bc * NN * TT + (size_t)m0 * TT;
#pragma unroll
  for (int j = 0; j < 12; ++j) {
    const int idx = j * 256 + tid;
    op[idx] = os[(idx / 12) * 13 + idx % 12];
  }
}

extern "C" void kernel_launch(void* const* d_in, const int* in_sizes, int n_in,
                              void* d_out, int out_size, void* d_ws, size_t ws_size,
                              hipStream_t stream) {
  const float* x = (const float*)d_in[0];
  const float* nv1 = (const float*)d_in[1];
  const float* nv2 = (const float*)d_in[2];
  const float* tv = (const float*)d_in[3];
  const float* kk = (const float*)d_in[4];
  const int* tind = (const int*)d_in[5];
  float* out = (float*)d_out;

  char* ws = (char*)d_ws;
  unsigned short* t1b  = (unsigned short*)(ws);            //  524288 B
  unsigned short* nv2b = (unsigned short*)(ws + 524288);   //  524288 B
  float* sumsp         = (float*)(ws + 1048576);           //  262144 B (8 x 8192 f32)
  unsigned short* yT   = (unsigned short*)(ws + 1310720);  // 3145728 B -> 4456448
  unsigned short* part = (unsigned short*)(ws + 4456448);  // 25165824 B (bf16)

  k_pre<<<512, 256, 0, stream>>>(x, nv1, nv2, tv, kk, tind, t1b, nv2b, yT);
  k_stats<<<dim3(128, NSPLIT), 256, 0, stream>>>(t1b, nv2b, sumsp);
  k_mega<<<dim3(128, NSPLIT), 256, 0, stream>>>(t1b, nv2b, yT, sumsp, part);
  k_reduce<<<dim3(32, 16), 256, 0, stream>>>(part, out);
}

// Round 15
// 172.061 us; speedup vs baseline: 1.0863x; 1.0690x over previous
//
#include <hip/hip_runtime.h>
#include <hip/hip_bf16.h>

// GDGCN: out[b,c,m,t] = sum_n softmax_row(relu(t1 nv2^T))[n,m] * x[b,c,n,t]
// t1 = nv1 @ (sum_d tv[d] k[d,:,:]);  N=8192, D=32, cols = B*C*T = 192.
// R26 == R21 verbatim (measured session best: 172.19us total, k_mega 71.2,
// WRITE 24.6MB, no spill, absmax 0.015625). The bias-fold arc (R22-R25)
// is conclusively net-negative: folding softmax normalization into
// k_mega's E-gen sits on a register-pressure knife-edge -- capped (256,4)
// it spills (24-60MB scratch), uncapped (256,3) it loses a resident block
// (occ 33->22.6%); best case 88.7us vs 71.2, while the 4-kernel pipeline
// it enables saves only ~8us. Reverting to the 5-kernel config where
// normalization is pre-applied to y in k_y (zero k_mega cost).
// Proven invariants: col-split waves + LDS-E dbuf (all m-split redesigns
// lost: R15/16/17), stage-top loads (R19), RAWBAR lgkmcnt-only, ESTR 70,
// setprio (T5), bf16 part (R21: halves part HBM traffic), RNE f2bf pack
// only (v_cvt_pk_bf16_f32 NOT RNE on gfx950, R14 fail).

#define NN 8192
#define DD 32
#define TT 12
#define NSPLIT 8
#define CHUNK 1024
#define ESTR 70  // LDS row stride (ushort)

typedef __attribute__((ext_vector_type(8))) short bf16x8;
typedef __attribute__((ext_vector_type(4))) short bf16x4;
typedef __attribute__((ext_vector_type(4))) float f32x4;

static __device__ __forceinline__ unsigned short f2bf(float f) {
  unsigned int u = __float_as_uint(f);
  u = (u + 0x7FFFu + ((u >> 16) & 1u)) >> 16;  // RNE bf16
  return (unsigned short)u;
}

static __device__ __forceinline__ float fexp2(float x) {
#if __has_builtin(__builtin_amdgcn_exp2f)
  return __builtin_amdgcn_exp2f(x);
#else
  return __builtin_exp2f(x);
#endif
}

// Raw barrier: LDS-visibility only (lgkmcnt). Global loads stay in flight.
#define RAWBAR()                                          \
  do {                                                    \
    asm volatile("s_waitcnt lgkmcnt(0)" ::: "memory");    \
    __builtin_amdgcn_sched_barrier(0);                    \
    __builtin_amdgcn_s_barrier();                         \
  } while (0)

// ---- fused: core = tv.k ; t1 = (nv1@core)*log2e (bf16) ; nv2 -> bf16 ; sums=0
// 128 blocks x 64 rows.
__global__ __launch_bounds__(256) void k_prep(const float* __restrict__ nv1,
                                              const float* __restrict__ nv2,
                                              const float* __restrict__ timevec,
                                              const float* __restrict__ kk,
                                              const int* __restrict__ tind,
                                              unsigned short* __restrict__ t1b,
                                              unsigned short* __restrict__ nv2b,
                                              float* __restrict__ sums) {
  __shared__ float cs[1024];
  const int tid = threadIdx.x;
  if (tid < 64) sums[blockIdx.x * 64 + tid] = 0.f;
  const float* tv = timevec + (size_t)tind[0] * DD;
  for (int idx = tid; idx < 1024; idx += 256) {
    float acc = 0.f;
#pragma unroll
    for (int d = 0; d < DD; ++d) acc += tv[d] * kk[d * 1024 + idx];
    cs[idx] = acc;
  }
  __syncthreads();
  const int nbase = blockIdx.x * 64;
  const int f = tid & 31, sub = tid >> 5;
#pragma unroll 4
  for (int it = 0; it < 8; ++it) {
    const int n = nbase + it * 8 + sub;
    const float* nr = nv1 + (size_t)n * DD;
    float acc = 0.f;
#pragma unroll
    for (int e = 0; e < DD; ++e) acc += nr[e] * cs[e * DD + f];
    t1b[(size_t)n * DD + f] = f2bf(acc * 1.4426950408889634f);  // fold log2(e)
  }
#pragma unroll 4
  for (int it = 0; it < 8; ++it) {
    const int idx = nbase * DD + it * 256 + tid;
    nv2b[idx] = f2bf(nv2[idx]);
  }
}

// ---- sums[n] += sum_m exp2(relu(t1[n].nv2[m]))  grid (128 n, 16 m-chunks) ----
// 512-m chunks -> 2048 blocks = 8 blocks/CU for latency hiding.
// 1-iter b-prefetch: loads of tile mt+64 issued before computing tile mt.
__global__ __launch_bounds__(256) void k_stats(const unsigned short* __restrict__ t1b,
                                               const unsigned short* __restrict__ nv2b,
                                               float* __restrict__ sums) {
  const int tid = threadIdx.x;
  const int w = tid >> 6, lane = tid & 63, q = lane >> 4, i16 = lane & 15;
  const int nbase = blockIdx.x * 64 + w * 16;
  bf16x8 a = *(const bf16x8*)(t1b + (size_t)(nbase + i16) * DD + q * 8);
  const f32x4 z4 = {0.f, 0.f, 0.f, 0.f};
  float s[4] = {0.f, 0.f, 0.f, 0.f};
  const int m0 = blockIdx.y * 512;
#define LDB(mt, u) (*(const bf16x8*)(nv2b + (size_t)((mt) + (u)*16 + i16) * DD + q * 8))
  bf16x8 b0 = LDB(m0, 0), b1 = LDB(m0, 1), b2 = LDB(m0, 2), b3 = LDB(m0, 3);
  for (int mt = m0; mt < m0 + 512; mt += 64) {
    const int mtn = (mt + 64 < m0 + 512) ? (mt + 64) : mt;  // clamp: dummy reload
    bf16x8 n0 = LDB(mtn, 0), n1 = LDB(mtn, 1), n2 = LDB(mtn, 2), n3 = LDB(mtn, 3);
    f32x4 d;
    d = __builtin_amdgcn_mfma_f32_16x16x32_bf16(a, b0, z4, 0, 0, 0);
#pragma unroll
    for (int r = 0; r < 4; ++r) s[r] += fexp2(fmaxf(d[r], 0.f));
    d = __builtin_amdgcn_mfma_f32_16x16x32_bf16(a, b1, z4, 0, 0, 0);
#pragma unroll
    for (int r = 0; r < 4; ++r) s[r] += fexp2(fmaxf(d[r], 0.f));
    d = __builtin_amdgcn_mfma_f32_16x16x32_bf16(a, b2, z4, 0, 0, 0);
#pragma unroll
    for (int r = 0; r < 4; ++r) s[r] += fexp2(fmaxf(d[r], 0.f));
    d = __builtin_amdgcn_mfma_f32_16x16x32_bf16(a, b3, z4, 0, 0, 0);
#pragma unroll
    for (int r = 0; r < 4; ++r) s[r] += fexp2(fmaxf(d[r], 0.f));
    b0 = n0; b1 = n1; b2 = n2; b3 = n3;
  }
#undef LDB
#pragma unroll
  for (int r = 0; r < 4; ++r)
    for (int off = 1; off < 16; off <<= 1) s[r] += __shfl_xor(s[r], off, 64);
  if (i16 == 0) {
#pragma unroll
    for (int r = 0; r < 4; ++r) atomicAdd(&sums[nbase + q * 4 + r], s[r]);
  }
}

// ---- yT[col][n] = bf16(x[bc][n][t] / sums[n]) via LDS transpose (pad 12->13) ----
__global__ __launch_bounds__(256) void k_y(const float* __restrict__ x,
                                           const float* __restrict__ sums,
                                           unsigned short* __restrict__ yT) {
  __shared__ float xs[3328];  // 256 * 13
  const int tid = threadIdx.x;
  const int n0 = blockIdx.x * 256;
  const int bc = blockIdx.y;
  const float* xp = x + (size_t)bc * NN * TT + (size_t)n0 * TT;
#pragma unroll
  for (int j = 0; j < 12; ++j) {
    const int idx = j * 256 + tid;
    xs[(idx / 12) * 13 + idx % 12] = xp[idx];
  }
  __syncthreads();
  const float rinv = 1.0f / sums[n0 + tid];
#pragma unroll
  for (int t = 0; t < 12; ++t)
    yT[(size_t)(bc * TT + t) * NN + n0 + tid] = f2bf(xs[tid * 13 + t] * rinv);
}

// ---- k_mega: part[nc][col][m] = sum_{n in chunk} E[n][m] * y[col][n] ----
// grid (128 m-blocks of 64, 8 chunks of 1024 n); 256 thr = 4 waves.
// Stage = 64 n, double-buffered Et[2][64][ESTR]. Gen: wave w -> E rows
// [w*16,+16) x 64 n. Acc: wave w -> coltiles [w*3,+3) x 4 m-subs x 2
// k-steps = 24 MFMAs, setprio-wrapped. One RAW barrier per stage.
// part output in bf16 (halves HBM write).
__global__ __launch_bounds__(256, 4) void k_mega(const unsigned short* __restrict__ t1b,
                                                 const unsigned short* __restrict__ nv2b,
                                                 const unsigned short* __restrict__ yT,
                                                 unsigned short* __restrict__ part) {
  const int tid = threadIdx.x;
  const int w = tid >> 6, lane = tid & 63, q = lane >> 4, i16 = lane & 15;
  const int mb = blockIdx.x * 64;
  const int nt0 = blockIdx.y * CHUNK;

  __shared__ unsigned short Ew[2][64][ESTR];  // 17920 B

  // gen B-frag (loop-invariant): B[d][m=i16] = nv2[mb + w*16 + i16][d]
  const bf16x8 bg = *(const bf16x8*)(nv2b + (size_t)(mb + w * 16 + i16) * DD + q * 8);
  const int rowm = w * 16 + i16;

  const f32x4 z4 = {0.f, 0.f, 0.f, 0.f};
  f32x4 acc[3][4];
#pragma unroll
  for (int c = 0; c < 3; ++c)
#pragma unroll
    for (int ms = 0; ms < 4; ++ms) acc[c][ms] = (f32x4){0.f, 0.f, 0.f, 0.f};

  // ---- prologue: generate stage 0 (64 n) into buf 0 ----
#pragma unroll
  for (int s = 0; s < 4; ++s) {
    bf16x8 at = *(const bf16x8*)(t1b + (size_t)(nt0 + s * 16 + i16) * DD + q * 8);
    f32x4 d = __builtin_amdgcn_mfma_f32_16x16x32_bf16(at, bg, z4, 0, 0, 0);
    bf16x4 e;
#pragma unroll
    for (int r = 0; r < 4; ++r) e[r] = (short)f2bf(fexp2(fmaxf(d[r], 0.f)));
    *(bf16x4*)&Ew[0][rowm][s * 16 + q * 4] = e;
  }
  RAWBAR();

  int p = 0;
  for (int st = 0; st < 16; ++st, p ^= 1) {
    const int nt = nt0 + st * 64;
    const bool more = (st < 15);

    // --- stage top: issue ALL global loads (y both halves, next t1) ---
    bf16x8 yfr0[3], yfr1[3];
#pragma unroll
    for (int c = 0; c < 3; ++c) {
      const unsigned short* ybase = yT + (size_t)((w * 3 + c) * 16 + i16) * NN + nt + q * 8;
      yfr0[c] = *(const bf16x8*)ybase;
      yfr1[c] = *(const bf16x8*)(ybase + 32);
    }
    bf16x8 atn[4];
    if (more) {
#pragma unroll
      for (int s = 0; s < 4; ++s)
        atn[s] = *(const bf16x8*)(t1b + (size_t)(nt + 64 + s * 16 + i16) * DD + q * 8);
    }

    // half-0 E operands
    bf16x8 efr[4];
#pragma unroll
    for (int ms = 0; ms < 4; ++ms)
      efr[ms] = *(const bf16x8*)&Ew[p][ms * 16 + i16][q * 8];

    // gen first half (s0,s1) for stage st+1
    f32x4 d0, d1;
    if (more) {
      d0 = __builtin_amdgcn_mfma_f32_16x16x32_bf16(atn[0], bg, z4, 0, 0, 0);
      d1 = __builtin_amdgcn_mfma_f32_16x16x32_bf16(atn[1], bg, z4, 0, 0, 0);
    }

    // acc k-step 0 (12 MFMAs), priority-boosted (T5)
    __builtin_amdgcn_s_setprio(1);
#pragma unroll
    for (int c = 0; c < 3; ++c)
#pragma unroll
      for (int ms = 0; ms < 4; ++ms)
        acc[c][ms] = __builtin_amdgcn_mfma_f32_16x16x32_bf16(yfr0[c], efr[ms], acc[c][ms], 0, 0, 0);
    __builtin_amdgcn_s_setprio(0);

    // exp2 + store s0,s1; gen + store s2,s3 (VALU overlaps MFMA pipes)
    if (more) {
      bf16x4 e0, e1;
#pragma unroll
      for (int r = 0; r < 4; ++r) {
        e0[r] = (short)f2bf(fexp2(fmaxf(d0[r], 0.f)));
        e1[r] = (short)f2bf(fexp2(fmaxf(d1[r], 0.f)));
      }
      *(bf16x4*)&Ew[p ^ 1][rowm][q * 4] = e0;
      *(bf16x4*)&Ew[p ^ 1][rowm][16 + q * 4] = e1;
      f32x4 d2 = __builtin_amdgcn_mfma_f32_16x16x32_bf16(atn[2], bg, z4, 0, 0, 0);
      f32x4 d3 = __builtin_amdgcn_mfma_f32_16x16x32_bf16(atn[3], bg, z4, 0, 0, 0);
      bf16x4 e2, e3;
#pragma unroll
      for (int r = 0; r < 4; ++r) {
        e2[r] = (short)f2bf(fexp2(fmaxf(d2[r], 0.f)));
        e3[r] = (short)f2bf(fexp2(fmaxf(d3[r], 0.f)));
      }
      *(bf16x4*)&Ew[p ^ 1][rowm][32 + q * 4] = e2;
      *(bf16x4*)&Ew[p ^ 1][rowm][48 + q * 4] = e3;
    }

    // half-1 E operands + acc (k-step 1: n 32..63)
#pragma unroll
    for (int ms = 0; ms < 4; ++ms)
      efr[ms] = *(const bf16x8*)&Ew[p][ms * 16 + i16][32 + q * 8];
    __builtin_amdgcn_s_setprio(1);
#pragma unroll
    for (int c = 0; c < 3; ++c)
#pragma unroll
      for (int ms = 0; ms < 4; ++ms)
        acc[c][ms] = __builtin_amdgcn_mfma_f32_16x16x32_bf16(yfr1[c], efr[ms], acc[c][ms], 0, 0, 0);
    __builtin_amdgcn_s_setprio(0);

    RAWBAR();  // buf p reads done; buf p^1 writes visible (lgkmcnt only)
  }

  // epilogue: lane holds col = (w*3+c)*16 + q*4 + r, m = mb + ms*16 + i16
  unsigned short* pp = part + (size_t)blockIdx.y * 192 * NN;
#pragma unroll
  for (int c = 0; c < 3; ++c)
#pragma unroll
    for (int ms = 0; ms < 4; ++ms) {
      const int colbase = (w * 3 + c) * 16 + q * 4;
      const int m = mb + ms * 16 + i16;
#pragma unroll
      for (int r = 0; r < 4; ++r)
        pp[(size_t)(colbase + r) * NN + m] = f2bf(acc[c][ms][r]);
    }
}

// ---- reduce NSPLIT bf16 partials + transpose to out[bc][m][t] (pad 12->13) ----
__global__ __launch_bounds__(256) void k_reduce(const unsigned short* __restrict__ part,
                                                float* __restrict__ out) {
  __shared__ float os[3328];  // 256 * 13
  const int tid = threadIdx.x;
  const int m0 = blockIdx.x * 256;
  const int bc = blockIdx.y;
#pragma unroll
  for (int t = 0; t < 12; ++t) {
    const int col = bc * TT + t;
    float s = 0.f;
#pragma unroll
    for (int nc = 0; nc < NSPLIT; ++nc) {
      const unsigned int u = part[((size_t)nc * 192 + col) * NN + m0 + tid];
      s += __uint_as_float(u << 16);
    }
    os[tid * 13 + t] = s;
  }
  __syncthreads();
  float* op = out + (size_t)bc * NN * TT + (size_t)m0 * TT;
#pragma unroll
  for (int j = 0; j < 12; ++j) {
    const int idx = j * 256 + tid;
    op[idx] = os[(idx / 12) * 13 + idx % 12];
  }
}

extern "C" void kernel_launch(void* const* d_in, const int* in_sizes, int n_in,
                              void* d_out, int out_size, void* d_ws, size_t ws_size,
                              hipStream_t stream) {
  const float* x = (const float*)d_in[0];
  const float* nv1 = (const float*)d_in[1];
  const float* nv2 = (const float*)d_in[2];
  const float* tv = (const float*)d_in[3];
  const float* kk = (const float*)d_in[4];
  const int* tind = (const int*)d_in[5];
  float* out = (float*)d_out;

  char* ws = (char*)d_ws;
  unsigned short* t1b  = (unsigned short*)(ws);            //  524288 B
  unsigned short* nv2b = (unsigned short*)(ws + 524288);   //  524288 B
  float* sums          = (float*)(ws + 1048576);           //   32768 B
  unsigned short* yT   = (unsigned short*)(ws + 1081344);  // 3145728 B -> 4227072
  unsigned short* part = (unsigned short*)(ws + 4227072);  // 25165824 B (bf16) -> 29392896

  k_prep<<<128, 256, 0, stream>>>(nv1, nv2, tv, kk, tind, t1b, nv2b, sums);
  k_stats<<<dim3(128, 16), 256, 0, stream>>>(t1b, nv2b, sums);
  k_y<<<dim3(32, 16), 256, 0, stream>>>(x, sums, yT);
  k_mega<<<dim3(128, NSPLIT), 256, 0, stream>>>(t1b, nv2b, yT, part);
  k_reduce<<<dim3(32, 16), 256, 0, stream>>>(part, out);
}